// Round 15
// baseline (57.620 us; speedup 1.0000x reference)
//
#include <hip/hip_runtime.h>
#include <hip/hip_bf16.h>
#include <math.h>

// y[n,o] = min_i (x[n,i] + w[o,i]) + bias[o]
// x: (32768,128) f32, w: (128,128) f32, bias: (128,) f32, out: (32768,128) f32
//
// R13 compute engine (proven: xr[64] stays resident, x fetched once) + fixed
// epilogue. Lane owns one row (x in 64 h2 VGPRs); wave owns 32 cols; w rows
// are wave-uniform vector loads (1 line/inst, 32KB L1/L2-resident, 2 batches
// of 8 uint4). Results transpose through a pad-65 LDS buffer so global stores
// are coalesced (2 rows x 32 cols per dword-store inst) -- kills R13's 154MB
// write amplification. Main loop uses NO LDS; epilogue uses 64 LDS insts.

typedef __fp16 h2 __attribute__((ext_vector_type(2)));
typedef __fp16 h4 __attribute__((ext_vector_type(4)));

constexpr int K = 128;

__global__ void cvt_w_kernel(const float* __restrict__ w, __fp16* __restrict__ wh) {
    int i = blockIdx.x * 256 + threadIdx.x;       // 4096 threads, 4 elems each
    float4 v = *(const float4*)(w + (size_t)i * 4);
    h2 a = __builtin_amdgcn_cvt_pkrtz(v.x, v.y);
    h2 b = __builtin_amdgcn_cvt_pkrtz(v.z, v.w);
    *(h4*)(wh + (size_t)i * 4) = __builtin_shufflevector(a, b, 0, 1, 2, 3);
}

__global__ __launch_bounds__(256, 2)
void minplus_kernel(const float* __restrict__ x,
                    const __fp16* __restrict__ wh,
                    const float* __restrict__ bias,
                    float* __restrict__ out)
{
    __shared__ float tbuf[4 * 32 * 65];          // 33,280 B; per-wave 32x64 pad-65

    const int tid  = threadIdx.x;
    const int lane = tid & 63;
    const int wv   = tid >> 6;                   // wave 0..3 -> cols wv*32..+31
    const int rowbase = blockIdx.x * 64;
    const int row  = rowbase + lane;             // lane owns this row

    // ---- my x row -> 64 h2 VGPRs (R13-proven resident pattern) ----
    const float4* xrow = (const float4*)(x + (size_t)row * K);
    h2 xr[64];
    #pragma unroll
    for (int q = 0; q < 32; ++q) {
        float4 v = xrow[q];
        xr[2 * q + 0] = __builtin_amdgcn_cvt_pkrtz(v.x, v.y);
        xr[2 * q + 1] = __builtin_amdgcn_cvt_pkrtz(v.z, v.w);
    }

    h2 hbig;
    hbig.x = (__fp16)65504.0f;
    hbig.y = (__fp16)65504.0f;

    float* wbuf = tbuf + wv * (32 * 65);

    for (int o = 0; o < 32; ++o) {
        const int col = wv * 32 + o;
        const uint4* wr = (const uint4*)(wh + (size_t)col * K);  // wave-uniform
        h2 a0 = hbig, a1 = hbig, a2 = hbig, a3 = hbig;

#define DO4(U, G)                                                             \
        {                                                                     \
            h2 s0 = xr[(G) + 0] + __builtin_bit_cast(h2, (U).x);              \
            a0 = __builtin_elementwise_min(a0, s0);                           \
            h2 s1 = xr[(G) + 1] + __builtin_bit_cast(h2, (U).y);              \
            a1 = __builtin_elementwise_min(a1, s1);                           \
            h2 s2 = xr[(G) + 2] + __builtin_bit_cast(h2, (U).z);              \
            a2 = __builtin_elementwise_min(a2, s2);                           \
            h2 s3 = xr[(G) + 3] + __builtin_bit_cast(h2, (U).w);              \
            a3 = __builtin_elementwise_min(a3, s3);                           \
        }
        {   // batch 1: k 0..63 (8 uint4 in flight, bounded VGPR)
            uint4 u0 = wr[0], u1 = wr[1], u2 = wr[2], u3 = wr[3];
            uint4 u4 = wr[4], u5 = wr[5], u6 = wr[6], u7 = wr[7];
            DO4(u0, 0)  DO4(u1, 4)  DO4(u2, 8)  DO4(u3, 12)
            DO4(u4, 16) DO4(u5, 20) DO4(u6, 24) DO4(u7, 28)
        }
        {   // batch 2: k 64..127
            uint4 u0 = wr[8],  u1 = wr[9],  u2 = wr[10], u3 = wr[11];
            uint4 u4 = wr[12], u5 = wr[13], u6 = wr[14], u7 = wr[15];
            DO4(u0, 32) DO4(u1, 36) DO4(u2, 40) DO4(u3, 44)
            DO4(u4, 48) DO4(u5, 52) DO4(u6, 56) DO4(u7, 60)
        }
#undef DO4

        h2 m = __builtin_elementwise_min(__builtin_elementwise_min(a0, a1),
                                         __builtin_elementwise_min(a2, a3));
        float r = fminf((float)m.x, (float)m.y) + bias[col];
        wbuf[o * 65 + lane] = r;                 // conflict-free ds_write_b32
    }

    __syncthreads();

    // ---- coalesced readback/store: pass p covers rows 2p,2p+1 x 32 cols ----
    const int cw = lane & 31;                    // col within wave
    const int rh = lane >> 5;                    // row half (0/1)
    #pragma unroll 4
    for (int p = 0; p < 32; ++p) {
        float v = wbuf[cw * 65 + 2 * p + rh];    // pad-65: conflict-free
        out[(size_t)(rowbase + 2 * p + rh) * K + wv * 32 + cw] = v;
    }
}

extern "C" void kernel_launch(void* const* d_in, const int* in_sizes, int n_in,
                              void* d_out, int out_size, void* d_ws, size_t ws_size,
                              hipStream_t stream) {
    const float* x    = (const float*)d_in[0];
    const float* w    = (const float*)d_in[1];
    const float* bias = (const float*)d_in[2];
    float* out = (float*)d_out;
    __fp16* wh = (__fp16*)d_ws;                  // 32 KB f16 copy of w

    cvt_w_kernel<<<16, 256, 0, stream>>>(w, wh);

    int nrows  = in_sizes[0] / K;                // 32768
    int blocks = nrows / 64;                     // 512
    minplus_kernel<<<blocks, 256, 0, stream>>>(x, wh, bias, out);
}

// Round 16
// 28.588 us; speedup vs baseline: 2.0155x; 2.0155x over previous
//
#include <hip/hip_runtime.h>
#include <hip/hip_bf16.h>
#include <math.h>

// y[n,o] = min_i (x[n,i] + w[o,i]) + bias[o]
// x: (32768,128) f32, w: (128,128) f32, bias: (128,) f32, out: (32768,128) f32
//
// Balanced-pipe config derived from R10-R12 per-CU arithmetic:
//   512 threads, BM=BN=128, 8x4 per-thread tile -> per kc: 12 ds_read_b128
//   per 256 pk-VALU. Per-CU: LDS 18.4k cyc (7.7us) vs VALU 16.4k (6.8us) --
//   first config where LDS pipe is not the binding floor.
// x staged ONCE (BN=128, no col split). w staged whole. f16 tiles, 256B rows,
// XOR swizzle byte^=(row&7)<<4 (rows 16m apart share the swizzle constant ->
// one v_xor per operand per kc). 64KB LDS, grid=256 (1 block/CU, 8 waves).

typedef __fp16 h2 __attribute__((ext_vector_type(2)));
typedef __fp16 h4 __attribute__((ext_vector_type(4)));
typedef __fp16 h8 __attribute__((ext_vector_type(8)));

constexpr int K  = 128;
constexpr int BM = 128;

__global__ __launch_bounds__(512, 2)
void minplus_kernel(const float* __restrict__ x,
                    const float* __restrict__ w,
                    const float* __restrict__ bias,
                    float* __restrict__ out)
{
    __shared__ char lds[65536];              // x: [0,32768), w: [32768,65536)

    const int tid = threadIdx.x;
    const float* xsrc = x + (size_t)blockIdx.x * BM * K;

    // ---- stage x (128x128) and w (128x128), f32 -> f16, swizzled ----
    #pragma unroll
    for (int p = 0; p < 8; ++p) {
        int c   = p * 512 + tid;             // float4-chunk id, 0..4095
        int row = c >> 5;                    // 0..127
        int q   = c & 31;
        float4 v = *(const float4*)(xsrc + row * K + q * 4);
        h2 a = __builtin_amdgcn_cvt_pkrtz(v.x, v.y);
        h2 b = __builtin_amdgcn_cvt_pkrtz(v.z, v.w);
        int byte = row * 256 + ((q * 8) ^ ((row & 7) << 4));
        *(h4*)(lds + byte) = __builtin_shufflevector(a, b, 0, 1, 2, 3);
    }
    #pragma unroll
    for (int p = 0; p < 8; ++p) {
        int c   = p * 512 + tid;
        int row = c >> 5;
        int q   = c & 31;
        float4 v = *(const float4*)(w + row * K + q * 4);
        h2 a = __builtin_amdgcn_cvt_pkrtz(v.x, v.y);
        h2 b = __builtin_amdgcn_cvt_pkrtz(v.z, v.w);
        int byte = 32768 + row * 256 + ((q * 8) ^ ((row & 7) << 4));
        *(h4*)(lds + byte) = __builtin_shufflevector(a, b, 0, 1, 2, 3);
    }
    __syncthreads();                         // the ONLY barrier

    const int ty  = tid >> 5;                // 0..15 : rows ty + 16m, m=0..7
    const int tx  = tid & 31;                // 0..31 : cols tx + 32n, n=0..3
    const int swx = (ty & 7) << 4;           // (ty+16m)&7 == ty&7
    const int sww = (tx & 7) << 4;           // (tx+32n)&7 == tx&7
    const char* xb = lds + ty * 256;
    const char* wb = lds + 32768 + tx * 256;

    h2 hbig;
    hbig.x = (__fp16)65504.0f;
    hbig.y = (__fp16)65504.0f;
    h2 acc[8][4];
    #pragma unroll
    for (int m = 0; m < 8; ++m)
        #pragma unroll
        for (int n = 0; n < 4; ++n)
            acc[m][n] = hbig;

    // ---- 16 chunks of 8 k-elems: 12 ds_read_b128 + 256 pk-VALU each ----
    #pragma unroll 2
    for (int kc = 0; kc < 16; ++kc) {
        const char* xr = xb + ((kc * 16) ^ swx);   // 1 v_xor
        const char* wr = wb + ((kc * 16) ^ sww);   // 1 v_xor
        h8 xv0 = *(const h8*)(xr + 0 * 4096);
        h8 xv1 = *(const h8*)(xr + 1 * 4096);
        h8 xv2 = *(const h8*)(xr + 2 * 4096);
        h8 xv3 = *(const h8*)(xr + 3 * 4096);
        h8 xv4 = *(const h8*)(xr + 4 * 4096);
        h8 xv5 = *(const h8*)(xr + 5 * 4096);
        h8 xv6 = *(const h8*)(xr + 6 * 4096);
        h8 xv7 = *(const h8*)(xr + 7 * 4096);
        h8 wv0 = *(const h8*)(wr + 0 * 8192);
        h8 wv1 = *(const h8*)(wr + 1 * 8192);
        h8 wv2 = *(const h8*)(wr + 2 * 8192);
        h8 wv3 = *(const h8*)(wr + 3 * 8192);

#define UPD(m, n, XV, WV)                                                     \
        {                                                                     \
            h8 t  = XV + WV;                 /* 4x v_pk_add_f16 */            \
            h2 t0 = __builtin_shufflevector(t, t, 0, 1);                      \
            h2 t1 = __builtin_shufflevector(t, t, 2, 3);                      \
            h2 t2 = __builtin_shufflevector(t, t, 4, 5);                      \
            h2 t3 = __builtin_shufflevector(t, t, 6, 7);                      \
            h2 u  = __builtin_elementwise_min(t0, t1);                        \
            h2 v  = __builtin_elementwise_min(t2, t3);                        \
            h2 uv = __builtin_elementwise_min(u, v);                          \
            acc[m][n] = __builtin_elementwise_min(acc[m][n], uv);             \
        }
#define ROW(m, XV)                                                            \
        UPD(m, 0, XV, wv0) UPD(m, 1, XV, wv1) UPD(m, 2, XV, wv2) UPD(m, 3, XV, wv3)
        ROW(0, xv0) ROW(1, xv1) ROW(2, xv2) ROW(3, xv3)
        ROW(4, xv4) ROW(5, xv5) ROW(6, xv6) ROW(7, xv7)
#undef ROW
#undef UPD
    }

    // ---- epilogue: f16 pair-reduce -> f32, + bias, coalesced store ----
    const int rowbase = blockIdx.x * BM + ty;
    #pragma unroll
    for (int n = 0; n < 4; ++n) {
        float b = bias[tx + 32 * n];
        #pragma unroll
        for (int m = 0; m < 8; ++m) {
            h2 a = acc[m][n];
            out[(size_t)(rowbase + 16 * m) * 128 + tx + 32 * n] =
                fminf((float)a.x, (float)a.y) + b;
        }
    }
}

extern "C" void kernel_launch(void* const* d_in, const int* in_sizes, int n_in,
                              void* d_out, int out_size, void* d_ws, size_t ws_size,
                              hipStream_t stream) {
    const float* x    = (const float*)d_in[0];
    const float* w    = (const float*)d_in[1];
    const float* bias = (const float*)d_in[2];
    float* out = (float*)d_out;

    int nrows  = in_sizes[0] / K;            // 32768
    int blocks = nrows / BM;                 // 256 -> 1 block/CU
    minplus_kernel<<<blocks, 512, 0, stream>>>(x, w, bias, out);
}